// Round 6
// baseline (835.019 us; speedup 1.0000x reference)
//
#include <hip/hip_runtime.h>

#define N_NODES 100000
#define N_EDGES 1600000
#define D 128
#define DE 16
#define G 512
#define EPSBN 1e-5f
#define ESLICE 4    // edge-hidden stream slices per graph (2 per fused kernel)
#define EPB 1024    // edges per block in k_scatter
#define EPT (EPB / 256)
#define SCHUNK 1024 // nodes per block in hierarchical scan
#define NSB ((N_NODES + SCHUNK - 1) / SCHUNK)  // 98
#define AGG_CH 16   // nodes per wave in agg kernels
#define AGGB ((N_NODES + 4 * AGG_CH - 1) / (4 * AGG_CH))  // 1563
#define DSHIFT 9
#define DBSZ 512
#define NBKT ((N_NODES + DBSZ - 1) / DBSZ)     // 196

typedef __bf16 bf16x8 __attribute__((ext_vector_type(8)));
typedef __bf16 bf16x4 __attribute__((ext_vector_type(4)));
typedef float f32x4 __attribute__((ext_vector_type(4)));

__device__ __forceinline__ float bf_lo(unsigned v) { return __uint_as_float(v << 16); }
__device__ __forceinline__ float bf_hi(unsigned v) { return __uint_as_float(v & 0xffff0000u); }

// ---------------- K0: init deg=1 (self loop), zero counters/accumulators ----------------
__global__ void k_init(int* __restrict__ deg, int* __restrict__ ecnt, int* __restrict__ dcnt,
                       float* __restrict__ gcnt, float* __restrict__ gsum,
                       float* __restrict__ esum) {
  int i = blockIdx.x * 256 + threadIdx.x;
  if (i < N_NODES) deg[i] = 1;
  if (i < G) { ecnt[i] = 0; gcnt[i] = 0.f; }
  if (i < NBKT) dcnt[i] = 0;
  if (i < G * D) { gsum[i] = 0.f; esum[i] = 0.f; }
}

// ---------------- K1: count in-degree, edges/graph, edges/dst-bucket (LDS bins) --------------
__global__ void k_count(const int* __restrict__ ei, const int* __restrict__ batch,
                        int* __restrict__ deg, int* __restrict__ ecnt, int* __restrict__ dcnt) {
  __shared__ int bins[G];
  __shared__ int dbins[NBKT];
  int tid = threadIdx.x;
  for (int i = tid; i < G; i += 256) bins[i] = 0;
  for (int i = tid; i < NBKT; i += 256) dbins[i] = 0;
  __syncthreads();
  int base = blockIdx.x * 4096;
  for (int t = tid; t < 4096; t += 256) {
    int e = base + t;
    if (e < N_EDGES) {
      int s = ei[e];
      int d = ei[N_EDGES + e];
      atomicAdd(&deg[d], 1);
      atomicAdd(&bins[batch[s]], 1);
      atomicAdd(&dbins[d >> DSHIFT], 1);
    }
  }
  __syncthreads();
  for (int i = tid; i < G; i += 256) if (bins[i]) atomicAdd(&ecnt[i], bins[i]);
  for (int i = tid; i < NBKT; i += 256) if (dbins[i]) atomicAdd(&dcnt[i], dbins[i]);
}

// ---------------- K2a: per-block partial sums of deg ----------------
__global__ __launch_bounds__(256) void k_scan_part(const int* __restrict__ deg,
                                                   int* __restrict__ part) {
  __shared__ int red[4];
  int tid = threadIdx.x;
  int base = blockIdx.x * SCHUNK + tid * 4;
  int s = 0;
  #pragma unroll
  for (int k = 0; k < 4; ++k) {
    int i = base + k;
    if (i < N_NODES) s += deg[i];
  }
  #pragma unroll
  for (int off = 32; off > 0; off >>= 1) s += __shfl_down(s, off);
  if ((tid & 63) == 0) red[tid >> 6] = s;
  __syncthreads();
  if (tid == 0) part[blockIdx.x] = red[0] + red[1] + red[2] + red[3];
}

// ---------------- K2b: single block: scan partials + ecnt + dcnt ----------------
__global__ void k_scan_mid(int* __restrict__ part, const int* __restrict__ ecnt,
                           int* __restrict__ ebs, int* __restrict__ ecur_pad,
                           const int* __restrict__ dcnt, int* __restrict__ dbs,
                           int* __restrict__ dcur_pad) {
  __shared__ int sb[512];
  int tid = threadIdx.x;  // 512 threads
  int v = (tid < NSB) ? part[tid] : 0;
  sb[tid] = v;
  __syncthreads();
  for (int off = 1; off < 512; off <<= 1) {
    int t = (tid >= off) ? sb[tid - off] : 0;
    __syncthreads();
    sb[tid] += t;
    __syncthreads();
  }
  if (tid < NSB) part[tid] = sb[tid] - v;
  __syncthreads();
  int v2 = ecnt[tid];
  sb[tid] = v2;
  __syncthreads();
  for (int off = 1; off < 512; off <<= 1) {
    int t = (tid >= off) ? sb[tid - off] : 0;
    __syncthreads();
    sb[tid] += t;
    __syncthreads();
  }
  ebs[tid] = sb[tid] - v2;
  ecur_pad[tid * 16] = sb[tid] - v2;
  __syncthreads();
  int v3 = (tid < NBKT) ? dcnt[tid] : 0;
  sb[tid] = v3;
  __syncthreads();
  for (int off = 1; off < 512; off <<= 1) {
    int t = (tid >= off) ? sb[tid - off] : 0;
    __syncthreads();
    sb[tid] += t;
    __syncthreads();
  }
  if (tid < NBKT) { dbs[tid] = sb[tid] - v3; dcur_pad[tid * 16] = sb[tid] - v3; }
}

// ---------------- K2c: write rs (exclusive prefix) + dinv ----------------
__global__ __launch_bounds__(256) void k_scan_write(const int* __restrict__ deg,
                                                    const int* __restrict__ part,
                                                    int* __restrict__ rs,
                                                    float* __restrict__ dinv) {
  __shared__ int sb[256];
  int tid = threadIdx.x;
  int base = blockIdx.x * SCHUNK + tid * 4;
  int d[4];
  int s = 0;
  #pragma unroll
  for (int k = 0; k < 4; ++k) {
    int i = base + k;
    d[k] = (i < N_NODES) ? deg[i] : 0;
    s += d[k];
  }
  sb[tid] = s;
  __syncthreads();
  for (int off = 1; off < 256; off <<= 1) {
    int t = (tid >= off) ? sb[tid - off] : 0;
    __syncthreads();
    sb[tid] += t;
    __syncthreads();
  }
  int ex = sb[tid] - s + part[blockIdx.x];
  #pragma unroll
  for (int k = 0; k < 4; ++k) {
    int i = base + k;
    if (i < N_NODES) {
      rs[i] = ex;
      dinv[i] = rsqrtf((float)d[k]);
      ex += d[k];
    }
  }
}

// ---------------- K4a: counting-sort edges: graph-sorted edge-ID list (4B/edge) + dst-bucket
// (src,dst) pairs. Block-local scans + staged writeback keep stores run-coalesced. ----------
__global__ __launch_bounds__(256) void k_scatter(const int* __restrict__ ei,
                                                 const int* __restrict__ batch,
                                                 int* __restrict__ ecur_pad,
                                                 int* __restrict__ dcur_pad,
                                                 int2* __restrict__ pairs,
                                                 int* __restrict__ idlist) {
  __shared__ int gbins[G];      // counts, then (in-place) block-local exclusive scan
  __shared__ int gbase[G];      // global reserved base per graph
  __shared__ int dbins[NBKT];   // counts, then block-local exclusive scan
  __shared__ int dbase[NBKT];   // global reserved base per bucket
  __shared__ int gsrc[EPB];     // scratch for dbins scan, then: slot -> local edge idx
  __shared__ int gdst[EPB];     // slot -> global idlist position
  __shared__ int dsrc[EPB];     // slot -> local edge idx (dst-bucket order)
  __shared__ int ddst[EPB];     // slot -> global pair index
  int tid = threadIdx.x;
  for (int i = tid; i < G; i += 256) gbins[i] = 0;
  for (int i = tid; i < NBKT; i += 256) dbins[i] = 0;
  __syncthreads();
  int e0 = blockIdx.x * EPB;
  int nvalid = N_EDGES - e0;
  if (nvalid > EPB) nvalid = EPB;
  // ---- phase 1: LDS rank computation ----
  int ge[EPT], gr[EPT], db[EPT], dr[EPT];
  #pragma unroll
  for (int k = 0; k < EPT; ++k) {
    int e = e0 + k * 256 + tid;
    ge[k] = -1;
    if (e < N_EDGES) {
      int s = ei[e], d = ei[N_EDGES + e];
      int g = batch[s];
      ge[k] = g;
      gr[k] = atomicAdd(&gbins[g], 1);
      db[k] = d >> DSHIFT;
      dr[k] = atomicAdd(&dbins[db[k]], 1);
    }
  }
  __syncthreads();
  // ---- phase 2: global reservations (one padded atomic per non-empty bin) ----
  for (int i = tid; i < G; i += 256) {
    int cnt = gbins[i];
    gbase[i] = cnt ? atomicAdd(&ecur_pad[i * 16], cnt) : 0;
  }
  for (int i = tid; i < NBKT; i += 256) {
    int cnt = dbins[i];
    dbase[i] = cnt ? atomicAdd(&dcur_pad[i * 16], cnt) : 0;
  }
  // ---- phase 2b: block-local exclusive scans (fused Hillis-Steele, shared barriers) ----
  // gbins: 512 entries, 2 per thread, in place. dbins: 196 entries via gsrc[0..255] scratch.
  int v0 = gbins[tid], v1 = gbins[tid + 256];
  int vd = (tid < NBKT) ? dbins[tid] : 0;
  gsrc[tid] = vd;
  __syncthreads();
  for (int off = 1; off < 512; off <<= 1) {
    int a = (tid >= off) ? gbins[tid - off] : 0;
    int b = gbins[tid + 256 - off];   // tid+256 >= off always (off <= 256)
    int c = (off < 256 && tid >= off) ? gsrc[tid - off] : 0;
    __syncthreads();
    gbins[tid] += a;
    gbins[tid + 256] += b;
    if (off < 256) gsrc[tid] += c;
    __syncthreads();
  }
  gbins[tid] -= v0;          // inclusive -> exclusive (own slots only)
  gbins[tid + 256] -= v1;
  if (tid < NBKT) dbins[tid] = gsrc[tid] - vd;
  __syncthreads();
  // ---- phase 3: stage (local edge idx, global dst) per sorted slot ----
  #pragma unroll
  for (int k = 0; k < EPT; ++k) {
    if (ge[k] >= 0) {
      int el = k * 256 + tid;
      int g = ge[k];
      int sG = gbins[g] + gr[k];
      gsrc[sG] = el;
      gdst[sG] = gbase[g] + gr[k];
      int bkt = db[k];
      int sD = dbins[bkt] + dr[k];
      dsrc[sD] = el;
      ddst[sD] = dbase[bkt] + dr[k];
    }
  }
  __syncthreads();
  // ---- phase 4a: idlist writeback in graph-sorted order (runs of consecutive positions) ----
  for (int p = tid; p < nvalid; p += 256) {
    idlist[gdst[p]] = e0 + gsrc[p];
  }
  // ---- phase 4b: pair writeback in bucket-sorted order (ei re-reads hit L1/L2) ----
  for (int p = tid; p < nvalid; p += 256) {
    int e = e0 + dsrc[p];
    pairs[ddst[p]] = make_int2(ei[e], ei[N_EDGES + e]);
  }
}

// ---------------- K4b: per-bucket CSR fill — block exclusively owns 512 nodes; cursors in LDS,
// nbr writes confined to the bucket's contiguous CSR range (no global atomics, no line thrash)
__global__ __launch_bounds__(256) void k_scatter_nbr(const int2* __restrict__ pairs,
                                                     const int* __restrict__ dbs,
                                                     const int* __restrict__ dcnt,
                                                     const int* __restrict__ rs,
                                                     int* __restrict__ nbr) {
  __shared__ int cur[DBSZ];
  int tid = threadIdx.x;
  int bkt = blockIdx.x;
  int nodeBase = bkt << DSHIFT;
  for (int l = tid; l < DBSZ; l += 256) {
    int node = nodeBase + l;
    cur[l] = (node < N_NODES) ? rs[node] : 0;
  }
  __syncthreads();
  int start = dbs[bkt], n = dcnt[bkt];
  for (int i = tid; i < n; i += 256) {
    int2 p = pairs[start + i];
    int pos = atomicAdd(&cur[p.y - nodeBase], 1);
    nbr[pos] = p.x;
  }
}

// ---------------- K5pre: convert W (128x128 fp32) to MFMA B-fragment layout bf16 -------------
// Wf[((kc*8+cb)*64+lane)*8+j] = W[kc*32+(lane>>4)*8+j][cb*16+(lane&15)]
__global__ void k_prep_w(const float* __restrict__ W, __bf16* __restrict__ Wf) {
  int tid = threadIdx.x;
  for (int idx = blockIdx.x * 256 + tid; idx < 16384; idx += 8 * 256) {
    int j = idx & 7;
    int lane = (idx >> 3) & 63;
    int cb = (idx >> 9) & 7;
    int kc = idx >> 12;
    int k = kc * 32 + (lane >> 4) * 8 + j;
    int n = cb * 16 + (lane & 15);
    Wf[idx] = (__bf16)W[k * 128 + n];
  }
}

// ---------------- K5/K7: out(bf16) = (X @ W) * dinv[row] via bf16 MFMA ----------------------
// 64-row block tile; X staged to LDS bf16 (row pad +8 -> conflict-free b128); W frags global.
__global__ __launch_bounds__(256) void k_gemm_mfma(const float* __restrict__ X,
                                                   const __bf16* __restrict__ Wf,
                                                   const float* __restrict__ dinv,
                                                   __bf16* __restrict__ out) {
  __shared__ __bf16 sXb[64][136];
  int tid = threadIdx.x;
  int wave = tid >> 6, lane = tid & 63;
  int m = lane & 15, kg = lane >> 4;
  int base = blockIdx.x * 64;
  // stage 64 x 128 fp32 -> bf16 LDS
  #pragma unroll
  for (int i = 0; i < 8; ++i) {
    int idx = tid + i * 256;          // 2048 float4 chunks
    int r = idx >> 5, cq = idx & 31;
    int row = base + r;
    float4 v = make_float4(0.f, 0.f, 0.f, 0.f);
    if (row < N_NODES) v = *(const float4*)(X + (size_t)row * 128 + cq * 4);
    bf16x4 h;
    h[0] = (__bf16)v.x; h[1] = (__bf16)v.y; h[2] = (__bf16)v.z; h[3] = (__bf16)v.w;
    *(bf16x4*)(&sXb[r][cq * 4]) = h;
  }
  __syncthreads();
  int r0 = wave * 16;
  f32x4 acc[8];
  #pragma unroll
  for (int cb = 0; cb < 8; ++cb) acc[cb] = (f32x4){0.f, 0.f, 0.f, 0.f};
  #pragma unroll
  for (int kc = 0; kc < 4; ++kc) {
    bf16x8 afrag = *(const bf16x8*)(&sXb[r0 + m][kc * 32 + kg * 8]);
    #pragma unroll
    for (int cb = 0; cb < 8; ++cb) {
      bf16x8 bfrag = *(const bf16x8*)(Wf + (((size_t)(kc * 8 + cb) * 64 + lane) << 3));
      acc[cb] = __builtin_amdgcn_mfma_f32_16x16x32_bf16(afrag, bfrag, acc[cb], 0, 0, 0);
    }
  }
  // epilogue: C row = kg*4+r, col = cb*16+m
  #pragma unroll
  for (int r = 0; r < 4; ++r) {
    int grow = base + r0 + kg * 4 + r;
    if (grow < N_NODES) {
      float dv = dinv[grow];
      #pragma unroll
      for (int cb = 0; cb < 8; ++cb)
        out[(size_t)grow * 128 + cb * 16 + m] = (__bf16)(acc[cb][r] * dv);
    }
  }
}

// ================= device bodies for the fused agg+edge kernels =================

// CSR aggregate (bf16 rows) + bias + BN + ReLU -> fp32 out (layer 1)
__device__ __forceinline__ void agg_bn_body(
    int blk, const unsigned* __restrict__ Au, const int* __restrict__ nbr,
    const int* __restrict__ rs, const int* __restrict__ deg,
    const float* __restrict__ dinv, const float* __restrict__ b,
    const float* __restrict__ gm, const float* __restrict__ bt,
    const float* __restrict__ m, const float* __restrict__ v,
    float* __restrict__ outB) {
  int tid = threadIdx.x;
  int wave = tid >> 6, lane = tid & 63;
  int c0 = lane * 2, c1 = c0 + 1;
  float sc0 = gm[c0] * rsqrtf(v[c0] + EPSBN), sc1 = gm[c1] * rsqrtf(v[c1] + EPSBN);
  float sh0 = bt[c0] - m[c0] * sc0, sh1 = bt[c1] - m[c1] * sc1;
  float bb0 = b[c0], bb1 = b[c1];
  int base = (blk * 4 + wave) * AGG_CH;
  for (int nn = 0; nn < AGG_CH; ++nn) {
    int i = base + nn;
    if (i >= N_NODES) return;
    unsigned sv = Au[(size_t)i * 64 + lane];
    float s0 = bf_lo(sv), s1 = bf_hi(sv);
    int j = rs[i];
    int end = j + deg[i] - 1;
    for (; j + 3 < end; j += 4) {
      int n0 = nbr[j], n1 = nbr[j + 1], n2 = nbr[j + 2], n3 = nbr[j + 3];
      unsigned a0 = Au[(size_t)n0 * 64 + lane];
      unsigned a1 = Au[(size_t)n1 * 64 + lane];
      unsigned a2 = Au[(size_t)n2 * 64 + lane];
      unsigned a3 = Au[(size_t)n3 * 64 + lane];
      s0 += bf_lo(a0) + bf_lo(a1) + bf_lo(a2) + bf_lo(a3);
      s1 += bf_hi(a0) + bf_hi(a1) + bf_hi(a2) + bf_hi(a3);
    }
    for (; j < end; ++j) {
      unsigned a = Au[(size_t)nbr[j] * 64 + lane];
      s0 += bf_lo(a); s1 += bf_hi(a);
    }
    float dv = dinv[i];
    float y0 = fmaxf((dv * s0 + bb0) * sc0 + sh0, 0.f);
    float y1 = fmaxf((dv * s1 + bb1) * sc1 + sh1, 0.f);
    *(float2*)(outB + (size_t)i * 128 + c0) = make_float2(y0, y1);
  }
}

// CSR aggregate + BN + ReLU + sorted-batch mean-pool (layer 2)
__device__ __forceinline__ void agg_bn_pool_body(
    int blk, const unsigned* __restrict__ Au, const int* __restrict__ nbr,
    const int* __restrict__ rs, const int* __restrict__ deg,
    const float* __restrict__ dinv, const int* __restrict__ batch,
    const float* __restrict__ b, const float* __restrict__ gm,
    const float* __restrict__ bt, const float* __restrict__ m,
    const float* __restrict__ v, float* __restrict__ gsum,
    float* __restrict__ gcnt) {
  int tid = threadIdx.x;
  int wave = tid >> 6, lane = tid & 63;
  int c0 = lane * 2, c1 = c0 + 1;
  float sc0 = gm[c0] * rsqrtf(v[c0] + EPSBN), sc1 = gm[c1] * rsqrtf(v[c1] + EPSBN);
  float sh0 = bt[c0] - m[c0] * sc0, sh1 = bt[c1] - m[c1] * sc1;
  float bb0 = b[c0], bb1 = b[c1];
  int base = (blk * 4 + wave) * AGG_CH;
  if (base >= N_NODES) return;
  float acc0 = 0.f, acc1 = 0.f, cnt = 0.f;
  int curg = -1;
  for (int nn = 0; nn < AGG_CH; ++nn) {
    int i = base + nn;
    if (i >= N_NODES) break;
    int bg = batch[i];
    if (bg != curg) {
      if (curg >= 0) {
        atomicAdd(&gsum[(size_t)curg * 128 + c0], acc0);
        atomicAdd(&gsum[(size_t)curg * 128 + c1], acc1);
        if (lane == 0) atomicAdd(&gcnt[curg], cnt);
      }
      acc0 = 0.f; acc1 = 0.f; cnt = 0.f; curg = bg;
    }
    unsigned sv = Au[(size_t)i * 64 + lane];
    float s0 = bf_lo(sv), s1 = bf_hi(sv);
    int j = rs[i];
    int end = j + deg[i] - 1;
    for (; j + 3 < end; j += 4) {
      int n0 = nbr[j], n1 = nbr[j + 1], n2 = nbr[j + 2], n3 = nbr[j + 3];
      unsigned a0 = Au[(size_t)n0 * 64 + lane];
      unsigned a1 = Au[(size_t)n1 * 64 + lane];
      unsigned a2 = Au[(size_t)n2 * 64 + lane];
      unsigned a3 = Au[(size_t)n3 * 64 + lane];
      s0 += bf_lo(a0) + bf_lo(a1) + bf_lo(a2) + bf_lo(a3);
      s1 += bf_hi(a0) + bf_hi(a1) + bf_hi(a2) + bf_hi(a3);
    }
    for (; j < end; ++j) {
      unsigned a = Au[(size_t)nbr[j] * 64 + lane];
      s0 += bf_lo(a); s1 += bf_hi(a);
    }
    float dv = dinv[i];
    acc0 += fmaxf((dv * s0 + bb0) * sc0 + sh0, 0.f);
    acc1 += fmaxf((dv * s1 + bb1) * sc1 + sh1, 0.f);
    cnt += 1.f;
  }
  if (curg >= 0) {
    atomicAdd(&gsum[(size_t)curg * 128 + c0], acc0);
    atomicAdd(&gsum[(size_t)curg * 128 + c1], acc1);
    if (lane == 0) atomicAdd(&gcnt[curg], cnt);
  }
}

// edge-hidden body: per-graph sum of relu(ea[id] @ We1 + be1), R5 all-lane gather structure.
// slice in [0,ESLICE); sid = slice*4+wave over nstream=16 total streams per graph.
__device__ __forceinline__ void edge_hidden_body(
    int g, int slice, const float* __restrict__ edge_attr,
    const int* __restrict__ idlist, const int* __restrict__ ebs,
    const int* __restrict__ ecnt, const float* __restrict__ We1,
    const float* __restrict__ be1, float* __restrict__ esum) {
  int tid = threadIdx.x;
  int wave = tid >> 6;
  int lane = tid & 63;
  int n = lane & 15;
  int kg = lane >> 4;          // 0..3
  int toff = kg >> 1;          // which tile of the pair this lane gathers for
  int cp = kg & 1;             // which 32B chunk-pair of the row

  bf16x8 bfrag[8];
  float biasv[8];
  #pragma unroll
  for (int blk = 0; blk < 8; ++blk) {
    #pragma unroll
    for (int j = 0; j < 8; ++j) {
      int k = kg * 8 + j;
      float w = (k < DE) ? We1[k * 128 + blk * 16 + n] : 0.f;
      bfrag[blk][j] = (__bf16)w;
    }
    biasv[blk] = be1[blk * 16 + n];
  }

  int start = ebs[g], cnt = ecnt[g];
  int lim = start + cnt;
  int ntiles = (cnt + 15) >> 4;
  const int nstream = ESLICE * 4;
  int sid = slice * 4 + wave;
  int tpc = (ntiles + nstream - 1) / nstream;
  int t0 = sid * tpc;
  int t1 = t0 + tpc; if (t1 > ntiles) t1 = ntiles;

  float racc[8] = {0.f, 0.f, 0.f, 0.f, 0.f, 0.f, 0.f, 0.f};

  auto compute_tile = [&](int t, bf16x8 afrag) {
    int jb = start + (t << 4);
    if (jb + 16 <= lim) {
      #pragma unroll
      for (int blk = 0; blk < 8; ++blk) {
        f32x4 acc = {0.f, 0.f, 0.f, 0.f};
        acc = __builtin_amdgcn_mfma_f32_16x16x32_bf16(afrag, bfrag[blk], acc, 0, 0, 0);
        #pragma unroll
        for (int r = 0; r < 4; ++r)
          racc[blk] += fmaxf(acc[r] + biasv[blk], 0.f);
      }
    } else {
      #pragma unroll
      for (int blk = 0; blk < 8; ++blk) {
        f32x4 acc = {0.f, 0.f, 0.f, 0.f};
        acc = __builtin_amdgcn_mfma_f32_16x16x32_bf16(afrag, bfrag[blk], acc, 0, 0, 0);
        #pragma unroll
        for (int r = 0; r < 4; ++r) {
          int rr = kg * 4 + r;
          if (jb + rr < lim) racc[blk] += fmaxf(acc[r] + biasv[blk], 0.f);
        }
      }
    }
  };

  for (int t = t0; t < t1; t += 2) {
    int tt = t + toff;
    int ttc = tt < ntiles ? tt : ntiles - 1;
    int slot = start + (ttc << 4) + n;
    int sc = slot < lim - 1 ? slot : lim - 1;
    int e = idlist[sc];
    const float4* q = (const float4*)(edge_attr + (size_t)e * DE + cp * 8);
    float4 f0 = q[0], f1 = q[1];
    union { bf16x8 v; int i[4]; } mine, swp;
    mine.v[0] = (__bf16)f0.x; mine.v[1] = (__bf16)f0.y;
    mine.v[2] = (__bf16)f0.z; mine.v[3] = (__bf16)f0.w;
    mine.v[4] = (__bf16)f1.x; mine.v[5] = (__bf16)f1.y;
    mine.v[6] = (__bf16)f1.z; mine.v[7] = (__bf16)f1.w;
    #pragma unroll
    for (int w2 = 0; w2 < 4; ++w2) swp.i[w2] = __shfl_xor(mine.i[w2], 32);
    bf16x8 a0 = {}, a1 = {};
    if (kg < 2) { a0 = mine.v; a1 = swp.v; }
    compute_tile(t, a0);
    if (t + 1 < t1) compute_tile(t + 1, a1);
  }

  #pragma unroll
  for (int blk = 0; blk < 8; ++blk) {
    float vsum = racc[blk];
    vsum += __shfl_xor(vsum, 16);
    vsum += __shfl_xor(vsum, 32);
    if (lane < 16) atomicAdd(&esum[(size_t)g * 128 + blk * 16 + n], vsum);
  }
}

// ---------------- K6+K9a fused: layer-1 aggregation co-scheduled with edge-hidden sids 0-7 ---
// Both are latency-bound (~91us each, VALU ~30%, nothing saturated); sharing CUs lets each
// workload's waves fill the other's stall slots.
__global__ __launch_bounds__(256) void k_fused_l1(
    const unsigned* __restrict__ Au, const int* __restrict__ nbr,
    const int* __restrict__ rs, const int* __restrict__ deg,
    const float* __restrict__ dinv, const float* __restrict__ b,
    const float* __restrict__ gm, const float* __restrict__ bt,
    const float* __restrict__ m, const float* __restrict__ v,
    float* __restrict__ outB,
    const float* __restrict__ edge_attr, const int* __restrict__ idlist,
    const int* __restrict__ ebs, const int* __restrict__ ecnt,
    const float* __restrict__ We1, const float* __restrict__ be1,
    float* __restrict__ esum) {
  int bid = blockIdx.x;
  if (bid < AGGB) {
    agg_bn_body(bid, Au, nbr, rs, deg, dinv, b, gm, bt, m, v, outB);
  } else {
    int eb = bid - AGGB;           // [0, 2G)
    edge_hidden_body(eb >> 1, eb & 1, edge_attr, idlist, ebs, ecnt, We1, be1, esum);
  }
}

// ---------------- K8+K9b fused: layer-2 agg+pool co-scheduled with edge-hidden sids 8-15 -----
__global__ __launch_bounds__(256) void k_fused_l2(
    const unsigned* __restrict__ Au, const int* __restrict__ nbr,
    const int* __restrict__ rs, const int* __restrict__ deg,
    const float* __restrict__ dinv, const int* __restrict__ batch,
    const float* __restrict__ b, const float* __restrict__ gm,
    const float* __restrict__ bt, const float* __restrict__ m,
    const float* __restrict__ v, float* __restrict__ gsum,
    float* __restrict__ gcnt,
    const float* __restrict__ edge_attr, const int* __restrict__ idlist,
    const int* __restrict__ ebs, const int* __restrict__ ecnt,
    const float* __restrict__ We1, const float* __restrict__ be1,
    float* __restrict__ esum) {
  int bid = blockIdx.x;
  if (bid < AGGB) {
    agg_bn_pool_body(bid, Au, nbr, rs, deg, dinv, batch, b, gm, bt, m, v, gsum, gcnt);
  } else {
    int eb = bid - AGGB;           // [0, 2G)
    edge_hidden_body(eb >> 1, 2 + (eb & 1), edge_attr, idlist, ebs, ecnt, We1, be1, esum);
  }
}

// ---------------- K10: graph mean + (edge mean hidden) @ We2 + be2 -> out ----------------
__global__ void k_final(const float* __restrict__ esum, const int* __restrict__ ecnt,
                        const float* __restrict__ gsum, const float* __restrict__ gcnt,
                        const float* __restrict__ We2, const float* __restrict__ be2,
                        float* __restrict__ out) {
  __shared__ float mh[128];
  int g = blockIdx.x, c = threadIdx.x;
  int ec = ecnt[g];
  mh[c] = (ec > 0) ? esum[(size_t)g * 128 + c] / (float)ec : 0.f;
  __syncthreads();
  float acc = 0.f;
  #pragma unroll 8
  for (int k = 0; k < 128; ++k) acc += mh[k] * We2[k * 128 + c];
  float er = (ec > 0) ? (acc + be2[c]) : 0.f;
  float gr = gsum[(size_t)g * 128 + c] / fmaxf(gcnt[g], 1.f);
  out[(size_t)g * 128 + c] = gr + er;
}

extern "C" void kernel_launch(void* const* d_in, const int* in_sizes, int n_in,
                              void* d_out, int out_size, void* d_ws, size_t ws_size,
                              hipStream_t stream) {
  const float* x        = (const float*)d_in[0];
  const int*   ei       = (const int*)d_in[1];
  const int*   batch    = (const int*)d_in[2];
  const float* edge_attr= (const float*)d_in[3];
  const float* W1 = (const float*)d_in[5];
  const float* b1 = (const float*)d_in[6];
  const float* g1 = (const float*)d_in[7];
  const float* bt1= (const float*)d_in[8];
  const float* m1 = (const float*)d_in[9];
  const float* v1 = (const float*)d_in[10];
  const float* W2 = (const float*)d_in[11];
  const float* b2 = (const float*)d_in[12];
  const float* g2 = (const float*)d_in[13];
  const float* bt2= (const float*)d_in[14];
  const float* m2 = (const float*)d_in[15];
  const float* v2 = (const float*)d_in[16];
  const float* We1= (const float*)d_in[17];
  const float* be1= (const float*)d_in[18];
  const float* We2= (const float*)d_in[19];
  const float* be2= (const float*)d_in[20];
  float* out = (float*)d_out;

  char* ws = (char*)d_ws;
  size_t off = 0;
  auto take = [&](size_t bytes) -> char* {
    char* p = ws + off;
    off += (bytes + 255) & ~(size_t)255;
    return p;
  };
  __bf16* A       = (__bf16*)take((size_t)N_NODES * 128 * 2);
  float*  B       = (float*) take((size_t)N_NODES * 128 * 4);
  float*  dinv    = (float*) take((size_t)N_NODES * 4);
  int*    deg     = (int*)   take((size_t)N_NODES * 4);
  int*    rs      = (int*)   take((size_t)N_NODES * 4);
  int*    nbr     = (int*)   take((size_t)(N_EDGES + N_NODES) * 4);
  int2*   pairs   = (int2*)  take((size_t)N_EDGES * 8);
  int*    idlist  = (int*)   take((size_t)N_EDGES * 4);
  __bf16* Wf1     = (__bf16*)take((size_t)16384 * 2);
  __bf16* Wf2     = (__bf16*)take((size_t)16384 * 2);
  int*    ecnt    = (int*)   take((size_t)G * 4);
  int*    ebs     = (int*)   take((size_t)G * 4);
  int*    ecur_pad= (int*)   take((size_t)G * 16 * 4);
  int*    dcnt    = (int*)   take((size_t)NBKT * 4);
  int*    dbs     = (int*)   take((size_t)NBKT * 4);
  int*    dcur_pad= (int*)   take((size_t)NBKT * 16 * 4);
  float*  gcnt    = (float*) take((size_t)G * 4);
  float*  esum    = (float*) take((size_t)G * 128 * 4);
  float*  gsum    = (float*) take((size_t)G * 128 * 4);
  int*    part    = (int*)   take((size_t)NSB * 4);

  k_init<<<(N_NODES + 255) / 256, 256, 0, stream>>>(deg, ecnt, dcnt, gcnt, gsum, esum);
  k_prep_w<<<8, 256, 0, stream>>>(W1, Wf1);
  k_prep_w<<<8, 256, 0, stream>>>(W2, Wf2);
  k_count<<<(N_EDGES + 4095) / 4096, 256, 0, stream>>>(ei, batch, deg, ecnt, dcnt);
  k_scan_part<<<NSB, 256, 0, stream>>>(deg, part);
  k_scan_mid<<<1, 512, 0, stream>>>(part, ecnt, ebs, ecur_pad, dcnt, dbs, dcur_pad);
  k_scan_write<<<NSB, 256, 0, stream>>>(deg, part, rs, dinv);
  k_scatter<<<(N_EDGES + EPB - 1) / EPB, 256, 0, stream>>>(ei, batch, ecur_pad, dcur_pad, pairs, idlist);
  k_scatter_nbr<<<NBKT, 256, 0, stream>>>(pairs, dbs, dcnt, rs, nbr);
  // layer 1 (+ edge-hidden sids 0-7 co-scheduled)
  k_gemm_mfma<<<(N_NODES + 63) / 64, 256, 0, stream>>>(x, Wf1, dinv, A);
  k_fused_l1<<<AGGB + 2 * G, 256, 0, stream>>>((const unsigned*)A, nbr, rs, deg, dinv,
                                               b1, g1, bt1, m1, v1, B,
                                               edge_attr, idlist, ebs, ecnt, We1, be1, esum);
  // layer 2 (+ pooling fused, + edge-hidden sids 8-15 co-scheduled)
  k_gemm_mfma<<<(N_NODES + 63) / 64, 256, 0, stream>>>(B, Wf2, dinv, A);
  k_fused_l2<<<AGGB + 2 * G, 256, 0, stream>>>((const unsigned*)A, nbr, rs, deg, dinv, batch,
                                               b2, g2, bt2, m2, v2, gsum, gcnt,
                                               edge_attr, idlist, ebs, ecnt, We1, be1, esum);
  k_final<<<G, 128, 0, stream>>>(esum, ecnt, gsum, gcnt, We2, be2, out);
}

// Round 7
// 690.659 us; speedup vs baseline: 1.2090x; 1.2090x over previous
//
#include <hip/hip_runtime.h>

#define N_NODES 100000
#define N_EDGES 1600000
#define D 128
#define DE 16
#define G 512
#define EPSBN 1e-5f
#define ESLICE 4    // blocks per graph in k_edge_hidden
#define EPB 1024    // edges per block in k_scatter
#define EPT (EPB / 256)
#define SCHUNK 1024 // nodes per block in hierarchical scan
#define NSB ((N_NODES + SCHUNK - 1) / SCHUNK)  // 98
#define AGG_CH 16   // nodes per wave in agg kernels
#define DSHIFT 9
#define DBSZ 512
#define NBKT ((N_NODES + DBSZ - 1) / DBSZ)     // 196
#define INITB ((N_NODES + 255) / 256)          // 391

typedef __bf16 bf16x8 __attribute__((ext_vector_type(8)));
typedef __bf16 bf16x4 __attribute__((ext_vector_type(4)));
typedef float f32x4 __attribute__((ext_vector_type(4)));

__device__ __forceinline__ float bf_lo(unsigned v) { return __uint_as_float(v << 16); }
__device__ __forceinline__ float bf_hi(unsigned v) { return __uint_as_float(v & 0xffff0000u); }

// ---------------- K0: merged init + W-prep (3 launches -> 1) ----------------
// blocks [0,INITB): init deg/counters/accums; [INITB,INITB+8): prep W1; next 8: prep W2.
__device__ __forceinline__ void prep_w_body(int pb, const float* __restrict__ W,
                                            __bf16* __restrict__ Wf) {
  int tid = threadIdx.x;
  for (int idx = pb * 256 + tid; idx < 16384; idx += 8 * 256) {
    int j = idx & 7;
    int lane = (idx >> 3) & 63;
    int cb = (idx >> 9) & 7;
    int kc = idx >> 12;
    int k = kc * 32 + (lane >> 4) * 8 + j;
    int n = cb * 16 + (lane & 15);
    Wf[idx] = (__bf16)W[k * 128 + n];
  }
}

__global__ void k_setup(int* __restrict__ deg, int* __restrict__ ecnt, int* __restrict__ dcnt,
                        float* __restrict__ gcnt, float* __restrict__ gsum,
                        float* __restrict__ esum,
                        const float* __restrict__ W1, __bf16* __restrict__ Wf1,
                        const float* __restrict__ W2, __bf16* __restrict__ Wf2) {
  int b = blockIdx.x;
  if (b < INITB) {
    int i = b * 256 + threadIdx.x;
    if (i < N_NODES) deg[i] = 1;
    if (i < G) { ecnt[i] = 0; gcnt[i] = 0.f; }
    if (i < NBKT) dcnt[i] = 0;
    if (i < G * D) { gsum[i] = 0.f; esum[i] = 0.f; }
  } else if (b < INITB + 8) {
    prep_w_body(b - INITB, W1, Wf1);
  } else {
    prep_w_body(b - INITB - 8, W2, Wf2);
  }
}

// ---------------- K1: count in-degree, edges/graph, edges/dst-bucket + bf16 feature cvt -----
// R7: fold the coalesced fp32->bf16 edge-feature conversion here (read 64B/edge, write
// 32B/edge, both edge-id-ordered => fully coalesced). This kernel already streams every
// edge and stalls on device atomics; the streaming hides under that latency. The bf16
// copy halves k_edge_hidden's gathered bytes AND line-transactions.
__global__ void k_count(const int* __restrict__ ei, const int* __restrict__ batch,
                        const float* __restrict__ edge_attr, __bf16* __restrict__ eaB,
                        int* __restrict__ deg, int* __restrict__ ecnt, int* __restrict__ dcnt) {
  __shared__ int bins[G];
  __shared__ int dbins[NBKT];
  int tid = threadIdx.x;
  for (int i = tid; i < G; i += 256) bins[i] = 0;
  for (int i = tid; i < NBKT; i += 256) dbins[i] = 0;
  __syncthreads();
  int base = blockIdx.x * 4096;
  for (int t = tid; t < 4096; t += 256) {
    int e = base + t;
    if (e < N_EDGES) {
      int s = ei[e];
      int d = ei[N_EDGES + e];
      atomicAdd(&deg[d], 1);
      atomicAdd(&bins[batch[s]], 1);
      atomicAdd(&dbins[d >> DSHIFT], 1);
      // coalesced bf16 conversion
      const float4* p = (const float4*)(edge_attr + (size_t)e * DE);
      float4 f0 = p[0], f1 = p[1], f2 = p[2], f3 = p[3];
      bf16x8 h0, h1;
      h0[0] = (__bf16)f0.x; h0[1] = (__bf16)f0.y; h0[2] = (__bf16)f0.z; h0[3] = (__bf16)f0.w;
      h0[4] = (__bf16)f1.x; h0[5] = (__bf16)f1.y; h0[6] = (__bf16)f1.z; h0[7] = (__bf16)f1.w;
      h1[0] = (__bf16)f2.x; h1[1] = (__bf16)f2.y; h1[2] = (__bf16)f2.z; h1[3] = (__bf16)f2.w;
      h1[4] = (__bf16)f3.x; h1[5] = (__bf16)f3.y; h1[6] = (__bf16)f3.z; h1[7] = (__bf16)f3.w;
      bf16x8* q = (bf16x8*)(eaB + (size_t)e * DE);
      q[0] = h0; q[1] = h1;
    }
  }
  __syncthreads();
  for (int i = tid; i < G; i += 256) if (bins[i]) atomicAdd(&ecnt[i], bins[i]);
  for (int i = tid; i < NBKT; i += 256) if (dbins[i]) atomicAdd(&dcnt[i], dbins[i]);
}

// ---------------- K2a: per-block partial sums of deg ----------------
__global__ __launch_bounds__(256) void k_scan_part(const int* __restrict__ deg,
                                                   int* __restrict__ part) {
  __shared__ int red[4];
  int tid = threadIdx.x;
  int base = blockIdx.x * SCHUNK + tid * 4;
  int s = 0;
  #pragma unroll
  for (int k = 0; k < 4; ++k) {
    int i = base + k;
    if (i < N_NODES) s += deg[i];
  }
  #pragma unroll
  for (int off = 32; off > 0; off >>= 1) s += __shfl_down(s, off);
  if ((tid & 63) == 0) red[tid >> 6] = s;
  __syncthreads();
  if (tid == 0) part[blockIdx.x] = red[0] + red[1] + red[2] + red[3];
}

// ---------------- K2b: single block: scan partials + ecnt + dcnt ----------------
__global__ void k_scan_mid(int* __restrict__ part, const int* __restrict__ ecnt,
                           int* __restrict__ ebs, int* __restrict__ ecur_pad,
                           const int* __restrict__ dcnt, int* __restrict__ dbs,
                           int* __restrict__ dcur_pad) {
  __shared__ int sb[512];
  int tid = threadIdx.x;  // 512 threads
  int v = (tid < NSB) ? part[tid] : 0;
  sb[tid] = v;
  __syncthreads();
  for (int off = 1; off < 512; off <<= 1) {
    int t = (tid >= off) ? sb[tid - off] : 0;
    __syncthreads();
    sb[tid] += t;
    __syncthreads();
  }
  if (tid < NSB) part[tid] = sb[tid] - v;
  __syncthreads();
  int v2 = ecnt[tid];
  sb[tid] = v2;
  __syncthreads();
  for (int off = 1; off < 512; off <<= 1) {
    int t = (tid >= off) ? sb[tid - off] : 0;
    __syncthreads();
    sb[tid] += t;
    __syncthreads();
  }
  ebs[tid] = sb[tid] - v2;
  ecur_pad[tid * 16] = sb[tid] - v2;
  __syncthreads();
  int v3 = (tid < NBKT) ? dcnt[tid] : 0;
  sb[tid] = v3;
  __syncthreads();
  for (int off = 1; off < 512; off <<= 1) {
    int t = (tid >= off) ? sb[tid - off] : 0;
    __syncthreads();
    sb[tid] += t;
    __syncthreads();
  }
  if (tid < NBKT) { dbs[tid] = sb[tid] - v3; dcur_pad[tid * 16] = sb[tid] - v3; }
}

// ---------------- K2c: write rs (exclusive prefix) + dinv ----------------
__global__ __launch_bounds__(256) void k_scan_write(const int* __restrict__ deg,
                                                    const int* __restrict__ part,
                                                    int* __restrict__ rs,
                                                    float* __restrict__ dinv) {
  __shared__ int sb[256];
  int tid = threadIdx.x;
  int base = blockIdx.x * SCHUNK + tid * 4;
  int d[4];
  int s = 0;
  #pragma unroll
  for (int k = 0; k < 4; ++k) {
    int i = base + k;
    d[k] = (i < N_NODES) ? deg[i] : 0;
    s += d[k];
  }
  sb[tid] = s;
  __syncthreads();
  for (int off = 1; off < 256; off <<= 1) {
    int t = (tid >= off) ? sb[tid - off] : 0;
    __syncthreads();
    sb[tid] += t;
    __syncthreads();
  }
  int ex = sb[tid] - s + part[blockIdx.x];
  #pragma unroll
  for (int k = 0; k < 4; ++k) {
    int i = base + k;
    if (i < N_NODES) {
      rs[i] = ex;
      dinv[i] = rsqrtf((float)d[k]);
      ex += d[k];
    }
  }
}

// ---------------- K4a: counting-sort edges: graph-sorted edge-ID list (4B/edge) + dst-bucket
// (src,dst) pairs. Block-local scans + staged writeback keep stores run-coalesced. ----------
__global__ __launch_bounds__(256) void k_scatter(const int* __restrict__ ei,
                                                 const int* __restrict__ batch,
                                                 int* __restrict__ ecur_pad,
                                                 int* __restrict__ dcur_pad,
                                                 int2* __restrict__ pairs,
                                                 int* __restrict__ idlist) {
  __shared__ int gbins[G];      // counts, then (in-place) block-local exclusive scan
  __shared__ int gbase[G];      // global reserved base per graph
  __shared__ int dbins[NBKT];   // counts, then block-local exclusive scan
  __shared__ int dbase[NBKT];   // global reserved base per bucket
  __shared__ int gsrc[EPB];     // scratch for dbins scan, then: slot -> local edge idx
  __shared__ int gdst[EPB];     // slot -> global idlist position
  __shared__ int dsrc[EPB];     // slot -> local edge idx (dst-bucket order)
  __shared__ int ddst[EPB];     // slot -> global pair index
  int tid = threadIdx.x;
  for (int i = tid; i < G; i += 256) gbins[i] = 0;
  for (int i = tid; i < NBKT; i += 256) dbins[i] = 0;
  __syncthreads();
  int e0 = blockIdx.x * EPB;
  int nvalid = N_EDGES - e0;
  if (nvalid > EPB) nvalid = EPB;
  // ---- phase 1: LDS rank computation ----
  int ge[EPT], gr[EPT], db[EPT], dr[EPT];
  #pragma unroll
  for (int k = 0; k < EPT; ++k) {
    int e = e0 + k * 256 + tid;
    ge[k] = -1;
    if (e < N_EDGES) {
      int s = ei[e], d = ei[N_EDGES + e];
      int g = batch[s];
      ge[k] = g;
      gr[k] = atomicAdd(&gbins[g], 1);
      db[k] = d >> DSHIFT;
      dr[k] = atomicAdd(&dbins[db[k]], 1);
    }
  }
  __syncthreads();
  // ---- phase 2: global reservations (one padded atomic per non-empty bin) ----
  for (int i = tid; i < G; i += 256) {
    int cnt = gbins[i];
    gbase[i] = cnt ? atomicAdd(&ecur_pad[i * 16], cnt) : 0;
  }
  for (int i = tid; i < NBKT; i += 256) {
    int cnt = dbins[i];
    dbase[i] = cnt ? atomicAdd(&dcur_pad[i * 16], cnt) : 0;
  }
  // ---- phase 2b: block-local exclusive scans (fused Hillis-Steele, shared barriers) ----
  // gbins: 512 entries, 2 per thread, in place. dbins: 196 entries via gsrc[0..255] scratch.
  int v0 = gbins[tid], v1 = gbins[tid + 256];
  int vd = (tid < NBKT) ? dbins[tid] : 0;
  gsrc[tid] = vd;
  __syncthreads();
  for (int off = 1; off < 512; off <<= 1) {
    int a = (tid >= off) ? gbins[tid - off] : 0;
    int b = gbins[tid + 256 - off];   // tid+256 >= off always (off <= 256)
    int c = (off < 256 && tid >= off) ? gsrc[tid - off] : 0;
    __syncthreads();
    gbins[tid] += a;
    gbins[tid + 256] += b;
    if (off < 256) gsrc[tid] += c;
    __syncthreads();
  }
  gbins[tid] -= v0;          // inclusive -> exclusive (own slots only)
  gbins[tid + 256] -= v1;
  if (tid < NBKT) dbins[tid] = gsrc[tid] - vd;
  __syncthreads();
  // ---- phase 3: stage (local edge idx, global dst) per sorted slot ----
  #pragma unroll
  for (int k = 0; k < EPT; ++k) {
    if (ge[k] >= 0) {
      int el = k * 256 + tid;
      int g = ge[k];
      int sG = gbins[g] + gr[k];
      gsrc[sG] = el;
      gdst[sG] = gbase[g] + gr[k];
      int bkt = db[k];
      int sD = dbins[bkt] + dr[k];
      dsrc[sD] = el;
      ddst[sD] = dbase[bkt] + dr[k];
    }
  }
  __syncthreads();
  // ---- phase 4a: idlist writeback in graph-sorted order (runs of consecutive positions) ----
  for (int p = tid; p < nvalid; p += 256) {
    idlist[gdst[p]] = e0 + gsrc[p];
  }
  // ---- phase 4b: pair writeback in bucket-sorted order (ei re-reads hit L1/L2) ----
  for (int p = tid; p < nvalid; p += 256) {
    int e = e0 + dsrc[p];
    pairs[ddst[p]] = make_int2(ei[e], ei[N_EDGES + e]);
  }
}

// ---------------- K4b: per-bucket CSR fill — block exclusively owns 512 nodes; cursors in LDS,
// nbr writes confined to the bucket's contiguous CSR range (no global atomics, no line thrash)
__global__ __launch_bounds__(256) void k_scatter_nbr(const int2* __restrict__ pairs,
                                                     const int* __restrict__ dbs,
                                                     const int* __restrict__ dcnt,
                                                     const int* __restrict__ rs,
                                                     int* __restrict__ nbr) {
  __shared__ int cur[DBSZ];
  int tid = threadIdx.x;
  int bkt = blockIdx.x;
  int nodeBase = bkt << DSHIFT;
  for (int l = tid; l < DBSZ; l += 256) {
    int node = nodeBase + l;
    cur[l] = (node < N_NODES) ? rs[node] : 0;
  }
  __syncthreads();
  int start = dbs[bkt], n = dcnt[bkt];
  for (int i = tid; i < n; i += 256) {
    int2 p = pairs[start + i];
    int pos = atomicAdd(&cur[p.y - nodeBase], 1);
    nbr[pos] = p.x;
  }
}

// ---------------- K5/K7: out(bf16) = (X @ W) * dinv[row] via bf16 MFMA ----------------------
// 64-row block tile; X staged to LDS bf16 (row pad +8 -> conflict-free b128); W frags global.
__global__ __launch_bounds__(256) void k_gemm_mfma(const float* __restrict__ X,
                                                   const __bf16* __restrict__ Wf,
                                                   const float* __restrict__ dinv,
                                                   __bf16* __restrict__ out) {
  __shared__ __bf16 sXb[64][136];
  int tid = threadIdx.x;
  int wave = tid >> 6, lane = tid & 63;
  int m = lane & 15, kg = lane >> 4;
  int base = blockIdx.x * 64;
  // stage 64 x 128 fp32 -> bf16 LDS
  #pragma unroll
  for (int i = 0; i < 8; ++i) {
    int idx = tid + i * 256;          // 2048 float4 chunks
    int r = idx >> 5, cq = idx & 31;
    int row = base + r;
    float4 v = make_float4(0.f, 0.f, 0.f, 0.f);
    if (row < N_NODES) v = *(const float4*)(X + (size_t)row * 128 + cq * 4);
    bf16x4 h;
    h[0] = (__bf16)v.x; h[1] = (__bf16)v.y; h[2] = (__bf16)v.z; h[3] = (__bf16)v.w;
    *(bf16x4*)(&sXb[r][cq * 4]) = h;
  }
  __syncthreads();
  int r0 = wave * 16;
  f32x4 acc[8];
  #pragma unroll
  for (int cb = 0; cb < 8; ++cb) acc[cb] = (f32x4){0.f, 0.f, 0.f, 0.f};
  #pragma unroll
  for (int kc = 0; kc < 4; ++kc) {
    bf16x8 afrag = *(const bf16x8*)(&sXb[r0 + m][kc * 32 + kg * 8]);
    #pragma unroll
    for (int cb = 0; cb < 8; ++cb) {
      bf16x8 bfrag = *(const bf16x8*)(Wf + (((size_t)(kc * 8 + cb) * 64 + lane) << 3));
      acc[cb] = __builtin_amdgcn_mfma_f32_16x16x32_bf16(afrag, bfrag, acc[cb], 0, 0, 0);
    }
  }
  // epilogue: C row = kg*4+r, col = cb*16+m
  #pragma unroll
  for (int r = 0; r < 4; ++r) {
    int grow = base + r0 + kg * 4 + r;
    if (grow < N_NODES) {
      float dv = dinv[grow];
      #pragma unroll
      for (int cb = 0; cb < 8; ++cb)
        out[(size_t)grow * 128 + cb * 16 + m] = (__bf16)(acc[cb][r] * dv);
    }
  }
}

// ---------------- K6: CSR aggregate (bf16 rows) + bias + BN + ReLU -> fp32 out ---------------
__global__ __launch_bounds__(256) void k_agg_bn(const unsigned* __restrict__ Au,
                                                const int* __restrict__ nbr,
                                                const int* __restrict__ rs,
                                                const int* __restrict__ deg,
                                                const float* __restrict__ dinv,
                                                const float* __restrict__ b,
                                                const float* __restrict__ gm,
                                                const float* __restrict__ bt,
                                                const float* __restrict__ m,
                                                const float* __restrict__ v,
                                                float* __restrict__ outB) {
  int tid = threadIdx.x;
  int wave = tid >> 6, lane = tid & 63;
  int c0 = lane * 2, c1 = c0 + 1;
  float sc0 = gm[c0] * rsqrtf(v[c0] + EPSBN), sc1 = gm[c1] * rsqrtf(v[c1] + EPSBN);
  float sh0 = bt[c0] - m[c0] * sc0, sh1 = bt[c1] - m[c1] * sc1;
  float bb0 = b[c0], bb1 = b[c1];
  int base = (blockIdx.x * 4 + wave) * AGG_CH;
  for (int nn = 0; nn < AGG_CH; ++nn) {
    int i = base + nn;
    if (i >= N_NODES) return;
    unsigned sv = Au[(size_t)i * 64 + lane];
    float s0 = bf_lo(sv), s1 = bf_hi(sv);
    int j = rs[i];
    int end = j + deg[i] - 1;
    for (; j + 3 < end; j += 4) {
      int n0 = nbr[j], n1 = nbr[j + 1], n2 = nbr[j + 2], n3 = nbr[j + 3];
      unsigned a0 = Au[(size_t)n0 * 64 + lane];
      unsigned a1 = Au[(size_t)n1 * 64 + lane];
      unsigned a2 = Au[(size_t)n2 * 64 + lane];
      unsigned a3 = Au[(size_t)n3 * 64 + lane];
      s0 += bf_lo(a0) + bf_lo(a1) + bf_lo(a2) + bf_lo(a3);
      s1 += bf_hi(a0) + bf_hi(a1) + bf_hi(a2) + bf_hi(a3);
    }
    for (; j < end; ++j) {
      unsigned a = Au[(size_t)nbr[j] * 64 + lane];
      s0 += bf_lo(a); s1 += bf_hi(a);
    }
    float dv = dinv[i];
    float y0 = fmaxf((dv * s0 + bb0) * sc0 + sh0, 0.f);
    float y1 = fmaxf((dv * s1 + bb1) * sc1 + sh1, 0.f);
    *(float2*)(outB + (size_t)i * 128 + c0) = make_float2(y0, y1);
  }
}

// ---------------- K8: CSR aggregate (bf16) + BN + ReLU + sorted-batch mean-pool --------------
__global__ __launch_bounds__(256) void k_agg_bn_pool(const unsigned* __restrict__ Au,
                                                     const int* __restrict__ nbr,
                                                     const int* __restrict__ rs,
                                                     const int* __restrict__ deg,
                                                     const float* __restrict__ dinv,
                                                     const int* __restrict__ batch,
                                                     const float* __restrict__ b,
                                                     const float* __restrict__ gm,
                                                     const float* __restrict__ bt,
                                                     const float* __restrict__ m,
                                                     const float* __restrict__ v,
                                                     float* __restrict__ gsum,
                                                     float* __restrict__ gcnt) {
  int tid = threadIdx.x;
  int wave = tid >> 6, lane = tid & 63;
  int c0 = lane * 2, c1 = c0 + 1;
  float sc0 = gm[c0] * rsqrtf(v[c0] + EPSBN), sc1 = gm[c1] * rsqrtf(v[c1] + EPSBN);
  float sh0 = bt[c0] - m[c0] * sc0, sh1 = bt[c1] - m[c1] * sc1;
  float bb0 = b[c0], bb1 = b[c1];
  int base = (blockIdx.x * 4 + wave) * AGG_CH;
  if (base >= N_NODES) return;
  float acc0 = 0.f, acc1 = 0.f, cnt = 0.f;
  int curg = -1;
  for (int nn = 0; nn < AGG_CH; ++nn) {
    int i = base + nn;
    if (i >= N_NODES) break;
    int bg = batch[i];
    if (bg != curg) {
      if (curg >= 0) {
        atomicAdd(&gsum[(size_t)curg * 128 + c0], acc0);
        atomicAdd(&gsum[(size_t)curg * 128 + c1], acc1);
        if (lane == 0) atomicAdd(&gcnt[curg], cnt);
      }
      acc0 = 0.f; acc1 = 0.f; cnt = 0.f; curg = bg;
    }
    unsigned sv = Au[(size_t)i * 64 + lane];
    float s0 = bf_lo(sv), s1 = bf_hi(sv);
    int j = rs[i];
    int end = j + deg[i] - 1;
    for (; j + 3 < end; j += 4) {
      int n0 = nbr[j], n1 = nbr[j + 1], n2 = nbr[j + 2], n3 = nbr[j + 3];
      unsigned a0 = Au[(size_t)n0 * 64 + lane];
      unsigned a1 = Au[(size_t)n1 * 64 + lane];
      unsigned a2 = Au[(size_t)n2 * 64 + lane];
      unsigned a3 = Au[(size_t)n3 * 64 + lane];
      s0 += bf_lo(a0) + bf_lo(a1) + bf_lo(a2) + bf_lo(a3);
      s1 += bf_hi(a0) + bf_hi(a1) + bf_hi(a2) + bf_hi(a3);
    }
    for (; j < end; ++j) {
      unsigned a = Au[(size_t)nbr[j] * 64 + lane];
      s0 += bf_lo(a); s1 += bf_hi(a);
    }
    float dv = dinv[i];
    acc0 += fmaxf((dv * s0 + bb0) * sc0 + sh0, 0.f);
    acc1 += fmaxf((dv * s1 + bb1) * sc1 + sh1, 0.f);
    cnt += 1.f;
  }
  if (curg >= 0) {
    atomicAdd(&gsum[(size_t)curg * 128 + c0], acc0);
    atomicAdd(&gsum[(size_t)curg * 128 + c1], acc1);
    if (lane == 0) atomicAdd(&gcnt[curg], cnt);
  }
}

// ---------------- K9: per-graph sum of relu(eaB[id] @ We1 + be1) via bf16 MFMA ---------------
// R7: gather pre-converted bf16 rows (32B). Lane l loads ONE 16B bf16x8: row (l&15)+((l>>5)<<4)
// of the tile-pair, half (l>>4)&1 -- direct A-fragment, no cvt. Tile-0 frag = own load
// (kg<2); tile-1 frag = shfl_xor(load, 32). Per iteration: 1 id load + 1 row load vs R5's
// 1 + 2 + 16 cvt; distinct-line transactions per load instr ~32 vs ~64.
__global__ __launch_bounds__(256) void k_edge_hidden(
    const __bf16* __restrict__ eaB,
    const int* __restrict__ idlist,
    const int* __restrict__ ebs, const int* __restrict__ ecnt,
    const float* __restrict__ We1, const float* __restrict__ be1,
    float* __restrict__ esum) {
  int tid = threadIdx.x;
  int wave = tid >> 6;
  int lane = tid & 63;
  int n = lane & 15;
  int kg = lane >> 4;                      // 0..3
  int rowIdx = (lane & 15) + ((lane >> 5) << 4);  // 0..31: which row of the tile-pair I load
  int half = (lane >> 4) & 1;              // which 16B half of the 32B row
  int g = blockIdx.x / ESLICE;
  int slice = blockIdx.x % ESLICE;

  bf16x8 bfrag[8];
  float biasv[8];
  #pragma unroll
  for (int blk = 0; blk < 8; ++blk) {
    #pragma unroll
    for (int j = 0; j < 8; ++j) {
      int k = kg * 8 + j;
      float w = (k < DE) ? We1[k * 128 + blk * 16 + n] : 0.f;
      bfrag[blk][j] = (__bf16)w;
    }
    biasv[blk] = be1[blk * 16 + n];
  }

  int start = ebs[g], cnt = ecnt[g];
  int lim = start + cnt;
  int ntiles = (cnt + 15) >> 4;
  const int nstream = ESLICE * 4;
  int sid = slice * 4 + wave;
  int tpc = (ntiles + nstream - 1) / nstream;
  int t0 = sid * tpc;
  int t1 = t0 + tpc; if (t1 > ntiles) t1 = ntiles;

  float racc[8] = {0.f, 0.f, 0.f, 0.f, 0.f, 0.f, 0.f, 0.f};

  auto compute_tile = [&](int t, bf16x8 afrag) {
    int jb = start + (t << 4);
    if (jb + 16 <= lim) {
      #pragma unroll
      for (int blk = 0; blk < 8; ++blk) {
        f32x4 acc = {0.f, 0.f, 0.f, 0.f};
        acc = __builtin_amdgcn_mfma_f32_16x16x32_bf16(afrag, bfrag[blk], acc, 0, 0, 0);
        #pragma unroll
        for (int r = 0; r < 4; ++r)
          racc[blk] += fmaxf(acc[r] + biasv[blk], 0.f);
      }
    } else {
      #pragma unroll
      for (int blk = 0; blk < 8; ++blk) {
        f32x4 acc = {0.f, 0.f, 0.f, 0.f};
        acc = __builtin_amdgcn_mfma_f32_16x16x32_bf16(afrag, bfrag[blk], acc, 0, 0, 0);
        #pragma unroll
        for (int r = 0; r < 4; ++r) {
          int rr = kg * 4 + r;
          if (jb + rr < lim) racc[blk] += fmaxf(acc[r] + biasv[blk], 0.f);
        }
      }
    }
  };

  for (int t = t0; t < t1; t += 2) {
    int slot = start + (t << 4) + rowIdx;
    int sc = slot < lim - 1 ? slot : lim - 1;
    int e = idlist[sc];
    union { bf16x8 v; int i[4]; } mine, swp;
    mine.v = *(const bf16x8*)(eaB + (size_t)e * DE + half * 8);
    #pragma unroll
    for (int w2 = 0; w2 < 4; ++w2) swp.i[w2] = __shfl_xor(mine.i[w2], 32);
    bf16x8 a0 = {}, a1 = {};
    if (kg < 2) { a0 = mine.v; a1 = swp.v; }   // kg>=2 lanes hold zero (K padding 16..31)
    compute_tile(t, a0);
    if (t + 1 < t1) compute_tile(t + 1, a1);
  }

  #pragma unroll
  for (int blk = 0; blk < 8; ++blk) {
    float vsum = racc[blk];
    vsum += __shfl_xor(vsum, 16);
    vsum += __shfl_xor(vsum, 32);
    if (lane < 16) atomicAdd(&esum[(size_t)g * 128 + blk * 16 + n], vsum);
  }
}

// ---------------- K10: graph mean + (edge mean hidden) @ We2 + be2 -> out ----------------
__global__ void k_final(const float* __restrict__ esum, const int* __restrict__ ecnt,
                        const float* __restrict__ gsum, const float* __restrict__ gcnt,
                        const float* __restrict__ We2, const float* __restrict__ be2,
                        float* __restrict__ out) {
  __shared__ float mh[128];
  int g = blockIdx.x, c = threadIdx.x;
  int ec = ecnt[g];
  mh[c] = (ec > 0) ? esum[(size_t)g * 128 + c] / (float)ec : 0.f;
  __syncthreads();
  float acc = 0.f;
  #pragma unroll 8
  for (int k = 0; k < 128; ++k) acc += mh[k] * We2[k * 128 + c];
  float er = (ec > 0) ? (acc + be2[c]) : 0.f;
  float gr = gsum[(size_t)g * 128 + c] / fmaxf(gcnt[g], 1.f);
  out[(size_t)g * 128 + c] = gr + er;
}

extern "C" void kernel_launch(void* const* d_in, const int* in_sizes, int n_in,
                              void* d_out, int out_size, void* d_ws, size_t ws_size,
                              hipStream_t stream) {
  const float* x        = (const float*)d_in[0];
  const int*   ei       = (const int*)d_in[1];
  const int*   batch    = (const int*)d_in[2];
  const float* edge_attr= (const float*)d_in[3];
  const float* W1 = (const float*)d_in[5];
  const float* b1 = (const float*)d_in[6];
  const float* g1 = (const float*)d_in[7];
  const float* bt1= (const float*)d_in[8];
  const float* m1 = (const float*)d_in[9];
  const float* v1 = (const float*)d_in[10];
  const float* W2 = (const float*)d_in[11];
  const float* b2 = (const float*)d_in[12];
  const float* g2 = (const float*)d_in[13];
  const float* bt2= (const float*)d_in[14];
  const float* m2 = (const float*)d_in[15];
  const float* v2 = (const float*)d_in[16];
  const float* We1= (const float*)d_in[17];
  const float* be1= (const float*)d_in[18];
  const float* We2= (const float*)d_in[19];
  const float* be2= (const float*)d_in[20];
  float* out = (float*)d_out;

  char* ws = (char*)d_ws;
  size_t off = 0;
  auto take = [&](size_t bytes) -> char* {
    char* p = ws + off;
    off += (bytes + 255) & ~(size_t)255;
    return p;
  };
  __bf16* A       = (__bf16*)take((size_t)N_NODES * 128 * 2);
  float*  B       = (float*) take((size_t)N_NODES * 128 * 4);
  float*  dinv    = (float*) take((size_t)N_NODES * 4);
  int*    deg     = (int*)   take((size_t)N_NODES * 4);
  int*    rs      = (int*)   take((size_t)N_NODES * 4);
  int*    nbr     = (int*)   take((size_t)(N_EDGES + N_NODES) * 4);
  int2*   pairs   = (int2*)  take((size_t)N_EDGES * 8);
  int*    idlist  = (int*)   take((size_t)N_EDGES * 4);
  __bf16* eaB     = (__bf16*)take((size_t)N_EDGES * DE * 2);
  __bf16* Wf1     = (__bf16*)take((size_t)16384 * 2);
  __bf16* Wf2     = (__bf16*)take((size_t)16384 * 2);
  int*    ecnt    = (int*)   take((size_t)G * 4);
  int*    ebs     = (int*)   take((size_t)G * 4);
  int*    ecur_pad= (int*)   take((size_t)G * 16 * 4);
  int*    dcnt    = (int*)   take((size_t)NBKT * 4);
  int*    dbs     = (int*)   take((size_t)NBKT * 4);
  int*    dcur_pad= (int*)   take((size_t)NBKT * 16 * 4);
  float*  gcnt    = (float*) take((size_t)G * 4);
  float*  esum    = (float*) take((size_t)G * 128 * 4);
  float*  gsum    = (float*) take((size_t)G * 128 * 4);
  int*    part    = (int*)   take((size_t)NSB * 4);

  k_setup<<<INITB + 16, 256, 0, stream>>>(deg, ecnt, dcnt, gcnt, gsum, esum,
                                          W1, Wf1, W2, Wf2);
  k_count<<<(N_EDGES + 4095) / 4096, 256, 0, stream>>>(ei, batch, edge_attr, eaB,
                                                       deg, ecnt, dcnt);
  k_scan_part<<<NSB, 256, 0, stream>>>(deg, part);
  k_scan_mid<<<1, 512, 0, stream>>>(part, ecnt, ebs, ecur_pad, dcnt, dbs, dcur_pad);
  k_scan_write<<<NSB, 256, 0, stream>>>(deg, part, rs, dinv);
  k_scatter<<<(N_EDGES + EPB - 1) / EPB, 256, 0, stream>>>(ei, batch, ecur_pad, dcur_pad, pairs, idlist);
  k_scatter_nbr<<<NBKT, 256, 0, stream>>>(pairs, dbs, dcnt, rs, nbr);
  const int aggBlocks = (N_NODES + 4 * AGG_CH - 1) / (4 * AGG_CH);
  // layer 1
  k_gemm_mfma<<<(N_NODES + 63) / 64, 256, 0, stream>>>(x, Wf1, dinv, A);
  k_agg_bn<<<aggBlocks, 256, 0, stream>>>((const unsigned*)A, nbr, rs, deg, dinv, b1, g1, bt1, m1, v1, B);
  // layer 2 (+ pooling fused)
  k_gemm_mfma<<<(N_NODES + 63) / 64, 256, 0, stream>>>(B, Wf2, dinv, A);
  k_agg_bn_pool<<<aggBlocks, 256, 0, stream>>>((const unsigned*)A, nbr, rs, deg, dinv, batch, b2, g2, bt2, m2, v2, gsum, gcnt);
  // edge path
  k_edge_hidden<<<G * ESLICE, 256, 0, stream>>>(eaB, idlist, ebs, ecnt, We1, be1, esum);
  k_final<<<G, 128, 0, stream>>>(esum, ecnt, gsum, gcnt, We2, be2, out);
}